// Round 15
// baseline (40.024 us; speedup 1.0000x reference)
//
#include <hip/hip_runtime.h>

#define LAMB_COORD 5.0f
#define LAMB_NOOBJ 0.5f
#define GEPS 1e-7f

// gt/pred: (B=16384, C=30, H=7, W=7) fp32. Record = 1470 floats = 30ch x 49 cells.
// R12/R14 geometry: 512 blocks x 512 threads (8 waves), RPB=32, 2 blocks/CU.
// Phase A (NEW): wave-local LDS staging, NO barriers:
//   each wave handles 4 records; per record: 8 contiguous float2 global loads
//   -> wave-private LDS buffer (double-buffered) -> per-cell stride-49 LDS
//   reads (conflict-free) -> GIoU/argmax/front loss. The 4-trip loop lets the
//   compiler pipeline record r+1's global loads under record r's DS/compute.
// Phase B: byte-identical to R12/R14 32-trip class stream.
// LDS: 8 waves x 2 bufs x 490 float2 = 62720 B + app 6272 B = ~69 KB.

#define RPB   32
#define CELLS (RPB * 49)          // 1568
#define CLS2R 490                 // float2 per record class region
#define FR2   245                 // float2 per record front (490 floats)

__global__ __launch_bounds__(512, 4) void yolo_loss_kernel(
        const float* __restrict__ gt, const float* __restrict__ pred,
        float* __restrict__ out) {
    // [wave][buf][0..244]=gt front, [245..489]=pred front
    __shared__ float2 stg[8][2][2 * FR2];   // 62720 B
    __shared__ float  app[CELLS];           // 6272 B
    __shared__ float  wsum[8];

    const int tid  = threadIdx.x;
    const int lane = tid & 63;
    const int wv   = tid >> 6;
    const size_t rec0 = (size_t)blockIdx.x * RPB;

    const float2* __restrict__ gf2 = (const float2*)gt;
    const float2* __restrict__ pf2 = (const float2*)pred;

    float s = 0.0f;

    // ---- Phase A: 4 records per wave, wave-local staged, double-buffered ----
    #pragma unroll
    for (int j = 0; j < 4; ++j) {
        const int buf = j & 1;
        const size_t rec = rec0 + wv * 4 + j;
        const size_t fb  = rec * 735;       // float2 base of record front

        // stage: contiguous float2 stream -> wave-private LDS
        #pragma unroll
        for (int k = 0; k < 4; ++k) {
            int idx = k * 64 + lane;
            if (idx > FR2 - 1) idx = FR2 - 1;     // clamp dup (same value)
            stg[wv][buf][idx]       = gf2[fb + idx];
            stg[wv][buf][FR2 + idx] = pf2[fb + idx];
        }

        // compute: lanes 0..48 each own one cell, read stride-49 from LDS
        const float* __restrict__ g = (const float*)&stg[wv][buf][0];
        const float* __restrict__ p = (const float*)&stg[wv][buf][FR2];
        if (lane < 49) {
            float gv[10], pv[10];
            #pragma unroll
            for (int c = 0; c < 10; ++c) {
                gv[c] = g[c * 49 + lane];
                pv[c] = p[c * 49 + lane];
            }

            const float gx1 = gv[0], gy1 = gv[1];
            const float gx2 = gv[0] + gv[2], gy2 = gv[1] + gv[3];
            const float ga  = (gx2 - gx1) * (gy2 - gy1);

            float l[2];
            #pragma unroll
            for (int k = 0; k < 2; ++k) {
                const int o = k * 5;
                float px1 = pv[o + 0], py1 = pv[o + 1];
                float px2 = px1 + pv[o + 2], py2 = py1 + pv[o + 3];
                float ix1 = fmaxf(gx1, px1), iy1 = fmaxf(gy1, py1);
                float ix2 = fminf(gx2, px2), iy2 = fminf(gy2, py2);
                float inter = fmaxf(ix2 - ix1, 0.0f) * fmaxf(iy2 - iy1, 0.0f);
                float pa  = (px2 - px1) * (py2 - py1);
                float uni = ga + pa - inter;
                float iou = inter / (uni + GEPS);
                float cx1 = fminf(gx1, px1), cy1 = fminf(gy1, py1);
                float cx2 = fmaxf(gx2, px2), cy2 = fmaxf(gy2, py2);
                float enc = (cx2 - cx1) * (cy2 - cy1);
                l[k] = 1.0f - (iou - (enc - uni) / (enc + GEPS));
            }

            // jnp.argmax first-max tie-break: arg = 1 iff l2 > l1
            float r0, r1;
            if (l[1] > l[0]) { r0 = 0.0f;   r1 = gv[9]; }
            else             { r0 = gv[4];  r1 = 0.0f;  }
            app[(wv * 4 + j) * 49 + lane] = fmaxf(r0, r1);

            float d;
            d = gv[0] - pv[0]; s += d * d * r0 * LAMB_COORD;
            d = gv[1] - pv[1]; s += d * d * r0 * LAMB_COORD;
            d = gv[5] - pv[5]; s += d * d * r1 * LAMB_COORD;
            d = gv[6] - pv[6]; s += d * d * r1 * LAMB_COORD;
            d = sqrtf(gv[2]) - sqrtf(pv[2]); s += d * d * r0 * LAMB_COORD;
            d = sqrtf(gv[3]) - sqrtf(pv[3]); s += d * d * r0 * LAMB_COORD;
            d = sqrtf(gv[7]) - sqrtf(pv[7]); s += d * d * r1 * LAMB_COORD;
            d = sqrtf(gv[8]) - sqrtf(pv[8]); s += d * d * r1 * LAMB_COORD;
            d = gv[4] - pv[4]; { float d2 = d * d; s += d2 * r0 + d2 * (1.0f - r0) * LAMB_NOOBJ; }
            d = gv[9] - pv[9]; { float d2 = d * d; s += d2 * r1 + d2 * (1.0f - r1) * LAMB_NOOBJ; }
        }
    }
    __syncthreads();   // app complete for all 32 records

    // ---- Phase B: class stream (channels 10..29), 32-trip record loop ----
    if (tid < CLS2R) {
        const int q = tid;
        int h0 = (2 * q) % 49;
        int h0n = (h0 == 48) ? 0 : h0 + 1;

        #pragma unroll 4
        for (int rr = 0; rr < RPB; ++rr) {
            const float2* __restrict__ gc = (const float2*)(gt   + (rec0 + rr) * 1470 + 490);
            const float2* __restrict__ pc = (const float2*)(pred + (rec0 + rr) * 1470 + 490);
            const int ab = rr * 49;

            float2 ga2 = gc[q];
            float2 pa2 = pc[q];
            float a0 = app[ab + h0];
            float a1 = app[ab + h0n];
            float d0 = ga2.x - pa2.x;
            float d1 = ga2.y - pa2.y;
            s += d0 * d0 * a0 + d1 * d1 * a1;
        }
    }

    // ---- Reduce: wave shuffle -> LDS -> one atomic per block ----
    #pragma unroll
    for (int off = 32; off > 0; off >>= 1)
        s += __shfl_down(s, off, 64);

    if (lane == 0) wsum[wv] = s;
    __syncthreads();
    if (tid == 0) {
        float b = 0.0f;
        #pragma unroll
        for (int w = 0; w < 8; ++w) b += wsum[w];
        atomicAdd(out, b);
    }
}

extern "C" void kernel_launch(void* const* d_in, const int* in_sizes, int n_in,
                              void* d_out, int out_size, void* d_ws, size_t ws_size,
                              hipStream_t stream) {
    const float* gt   = (const float*)d_in[0];
    const float* pred = (const float*)d_in[1];
    float* out = (float*)d_out;

    const int B = in_sizes[0] / 1470;    // 16384
    const int grid = B / RPB;            // 512

    hipMemsetAsync(out, 0, sizeof(float) * out_size, stream);
    yolo_loss_kernel<<<grid, 512, 0, stream>>>(gt, pred, out);
}